// Round 1
// baseline (222.071 us; speedup 1.0000x reference)
//
#include <hip/hip_runtime.h>
#include <math.h>

// Problem constants (fixed by setup_inputs): h [B=16, S=4096, D=512] fp32.
constexpr int B = 16;
constexpr int S = 4096;
constexpr int D = 512;
constexpr float MARGIN = 0.5f;
constexpr float EPS = 1e-8f;

// Each wave handles TG=4 consecutive t's; 4 waves per block.
constexpr int TG = 4;
constexpr int GROUPS_PER_BATCH = S / TG;            // 1024
constexpr int TOTAL_WAVES = B * GROUPS_PER_BATCH;   // 16384
constexpr int NBLOCKS = TOTAL_WAVES / 4;            // 4096

__device__ inline float dot8(const float4& x0, const float4& x1,
                             const float4& y0, const float4& y1) {
    return x0.x * y0.x + x0.y * y0.y + x0.z * y0.z + x0.w * y0.w +
           x1.x * y1.x + x1.y * y1.y + x1.z * y1.z + x1.w * y1.w;
}

__global__ __launch_bounds__(256) void tcl_partial(const float* __restrict__ h,
                                                   float* __restrict__ ws) {
    const int lane  = threadIdx.x & 63;
    const int wslot = threadIdx.x >> 6;
    const int wid   = blockIdx.x * 4 + wslot;
    const int b     = wid >> 10;               // GROUPS_PER_BATCH = 1024
    const int t0    = (wid & 1023) * TG;
    const float* base = h + (size_t)b * S * D;

    // Own rows t0..t0+3 in registers: lane covers elements [lane*8, lane*8+8)
    float4 a0[4], a1[4];
#pragma unroll
    for (int i = 0; i < 4; i++) {
        const float* p = base + (size_t)(t0 + i) * D + lane * 8;
        a0[i] = *(const float4*)p;
        a1[i] = *(const float4*)(p + 4);
    }

    // Per-lane partials
    float n2o[4];
#pragma unroll
    for (int i = 0; i < 4; i++) n2o[i] = dot8(a0[i], a1[i], a0[i], a1[i]);

    float dp[4][11];  // [i][0] = k=1 ; [i][1..10] = k=10..19
#pragma unroll
    for (int i = 0; i < 4; i++)
#pragma unroll
        for (int q = 0; q < 11; q++) dp[i][q] = 0.f;

    // k=1 dots among own rows
    dp[0][0] = dot8(a0[0], a1[0], a0[1], a1[1]);
    dp[1][0] = dot8(a0[1], a1[1], a0[2], a1[2]);
    dp[2][0] = dot8(a0[2], a1[2], a0[3], a1[3]);

    // Other rows: offsets {4, 10..22} from t0  (14 rows for 41 dots)
    float n2x[14];
#pragma unroll
    for (int j = 0; j < 14; j++) {
        const int off = (j == 0) ? 4 : (9 + j);
        const int s = t0 + off;
        float4 b0 = make_float4(0.f, 0.f, 0.f, 0.f);
        float4 b1 = make_float4(0.f, 0.f, 0.f, 0.f);
        if (s < S) {
            const float* p = base + (size_t)s * D + lane * 8;
            b0 = *(const float4*)p;
            b1 = *(const float4*)(p + 4);
        }
        n2x[j] = dot8(b0, b1, b0, b1);
        if (j == 0) {
            dp[3][0] += dot8(a0[3], a1[3], b0, b1);  // (t0+3, k=1)
        } else {
#pragma unroll
            for (int i = 0; i < 4; i++) {
                const int k = off - i;
                if (k >= 10 && k <= 19)
                    dp[i][k - 9] += dot8(a0[i], a1[i], b0, b1);
            }
        }
    }

    // Fused butterfly reduction of all 62 partials across the wave
#pragma unroll
    for (int o = 32; o > 0; o >>= 1) {
#pragma unroll
        for (int i = 0; i < 4; i++) n2o[i] += __shfl_down(n2o[i], o);
#pragma unroll
        for (int j = 0; j < 14; j++) n2x[j] += __shfl_down(n2x[j], o);
#pragma unroll
        for (int i = 0; i < 4; i++)
#pragma unroll
            for (int q = 0; q < 11; q++) dp[i][q] += __shfl_down(dp[i][q], o);
    }

    float local = 0.f;
    if (lane == 0) {
        const float w1 = 1.0f / ((float)B * (float)(S - 1));
        const float w2 = 1.0f / ((float)B * (float)(10 * S - 145));
        float no[4];
#pragma unroll
        for (int i = 0; i < 4; i++) no[i] = sqrtf(n2o[i]);
        float nx[14];
#pragma unroll
        for (int j = 0; j < 14; j++) nx[j] = sqrtf(n2x[j]);

#pragma unroll
        for (int i = 0; i < 4; i++) {
            const int t = t0 + i;
            if (t + 1 < S) {
                const float nb = (i < 3) ? no[i + 1] : nx[0];
                const float sim = dp[i][0] / fmaxf(no[i] * nb, EPS);
                local += w1 * (1.0f - sim);
            }
#pragma unroll
            for (int k = 10; k <= 19; k++) {
                if (t + k < S) {
                    const float nb = nx[i + k - 9];
                    const float sim = dp[i][k - 9] / fmaxf(no[i] * nb, EPS);
                    const float r = MARGIN - sim;
                    local += w2 * (r > 0.f ? r : 0.f);
                }
            }
        }
    }

    __shared__ float bsum[4];
    if (lane == 0) bsum[wslot] = local;
    __syncthreads();
    if (threadIdx.x == 0)
        ws[blockIdx.x] = bsum[0] + bsum[1] + bsum[2] + bsum[3];
}

__global__ __launch_bounds__(1024) void tcl_final(const float* __restrict__ ws,
                                                  float* __restrict__ out) {
    float v = 0.f;
    for (int j = threadIdx.x; j < NBLOCKS; j += 1024) v += ws[j];
#pragma unroll
    for (int o = 32; o > 0; o >>= 1) v += __shfl_down(v, o);
    __shared__ float s[16];
    if ((threadIdx.x & 63) == 0) s[threadIdx.x >> 6] = v;
    __syncthreads();
    if (threadIdx.x == 0) {
        float t = 0.f;
#pragma unroll
        for (int j = 0; j < 16; j++) t += s[j];
        out[0] = t;
    }
}

extern "C" void kernel_launch(void* const* d_in, const int* in_sizes, int n_in,
                              void* d_out, int out_size, void* d_ws, size_t ws_size,
                              hipStream_t stream) {
    const float* h = (const float*)d_in[0];
    float* out = (float*)d_out;
    float* ws = (float*)d_ws;  // needs NBLOCKS * 4 = 16 KB
    tcl_partial<<<NBLOCKS, 256, 0, stream>>>(h, ws);
    tcl_final<<<1, 1024, 0, stream>>>(ws, out);
}

// Round 2
// 209.088 us; speedup vs baseline: 1.0621x; 1.0621x over previous
//
#include <hip/hip_runtime.h>
#include <math.h>

// Problem constants (fixed by setup_inputs): h [B=16, S=4096, D=512] fp32.
constexpr int B = 16;
constexpr int S = 4096;
constexpr int D = 512;
constexpr float MARGIN = 0.5f;
constexpr float EPS = 1e-8f;

constexpr int TG = 4;                               // t's per wave
constexpr int GROUPS_PER_BATCH = S / TG;            // 1024
constexpr int TOTAL_WAVES = B * GROUPS_PER_BATCH;   // 16384
constexpr int NBLOCKS = TOTAL_WAVES / 4;            // 4096

__device__ inline float dot8(const float4& x0, const float4& x1,
                             const float4& y0, const float4& y1) {
    return x0.x * y0.x + x0.y * y0.y + x0.z * y0.z + x0.w * y0.w +
           x1.x * y1.x + x1.y * y1.y + x1.z * y1.z + x1.w * y1.w;
}

// v_add_f32_dpp step: x += dpp_move(x). old=0 + bound_ctrl(zero-fill) makes
// invalid-source lanes add 0 — unconditionally safe for sum reductions.
template <int CTRL>
__device__ __forceinline__ float dpp_add(float x) {
    int m = __builtin_amdgcn_update_dpp(0, __float_as_int(x), CTRL, 0xf, 0xf, true);
    return x + __int_as_float(m);
}

// Full wave64 sum via DPP (pure VALU, no LDS path). Result valid in lane 63.
__device__ __forceinline__ float wave_sum63(float x) {
    x = dpp_add<0x111>(x);  // row_shr:1
    x = dpp_add<0x112>(x);  // row_shr:2
    x = dpp_add<0x114>(x);  // row_shr:4
    x = dpp_add<0x118>(x);  // row_shr:8  -> lanes 15/31/47/63 hold row sums
    x = dpp_add<0x142>(x);  // row_bcast:15 -> lane31 += lane15, lane63 += lane47
    x = dpp_add<0x143>(x);  // row_bcast:31 -> lane63 += lane31
    return x;
}

__global__ __launch_bounds__(256) void tcl_partial(const float* __restrict__ h,
                                                   float* __restrict__ ws) {
    const int lane  = threadIdx.x & 63;
    const int wslot = threadIdx.x >> 6;
    const int wid   = blockIdx.x * 4 + wslot;
    const int b     = wid >> 10;               // GROUPS_PER_BATCH = 1024
    const int t0    = (wid & 1023) * TG;
    const float* base = h + (size_t)b * S * D;

    // Own rows t0..t0+3 in registers: lane covers elements [lane*8, lane*8+8)
    float4 a0[4], a1[4];
#pragma unroll
    for (int i = 0; i < 4; i++) {
        const float* p = base + (size_t)(t0 + i) * D + lane * 8;
        a0[i] = *(const float4*)p;
        a1[i] = *(const float4*)(p + 4);
    }

    float n2o[4];
#pragma unroll
    for (int i = 0; i < 4; i++) n2o[i] = dot8(a0[i], a1[i], a0[i], a1[i]);

    float dp[4][11];  // [i][0] = k=1 ; [i][1..10] = k=10..19
#pragma unroll
    for (int i = 0; i < 4; i++)
#pragma unroll
        for (int q = 0; q < 11; q++) dp[i][q] = 0.f;

    // k=1 dots among own rows
    dp[0][0] = dot8(a0[0], a1[0], a0[1], a1[1]);
    dp[1][0] = dot8(a0[1], a1[1], a0[2], a1[2]);
    dp[2][0] = dot8(a0[2], a1[2], a0[3], a1[3]);

    // Other rows: offsets {4, 10..22} from t0 (14 rows cover the 41 cross dots)
    float n2x[14];
#pragma unroll
    for (int j = 0; j < 14; j++) {
        const int off = (j == 0) ? 4 : (9 + j);
        const int s = t0 + off;
        float4 b0 = make_float4(0.f, 0.f, 0.f, 0.f);
        float4 b1 = make_float4(0.f, 0.f, 0.f, 0.f);
        if (s < S) {
            const float* p = base + (size_t)s * D + lane * 8;
            b0 = *(const float4*)p;
            b1 = *(const float4*)(p + 4);
        }
        n2x[j] = dot8(b0, b1, b0, b1);
        if (j == 0) {
            dp[3][0] += dot8(a0[3], a1[3], b0, b1);  // (t0+3, k=1)
        } else {
#pragma unroll
            for (int i = 0; i < 4; i++) {
                const int k = off - i;
                if (k >= 10 && k <= 19)
                    dp[i][k - 9] += dot8(a0[i], a1[i], b0, b1);
            }
        }
    }

    // DPP wave reduction of all 62 partials (pure VALU; results in lane 63)
#pragma unroll
    for (int i = 0; i < 4; i++) n2o[i] = wave_sum63(n2o[i]);
#pragma unroll
    for (int j = 0; j < 14; j++) n2x[j] = wave_sum63(n2x[j]);
#pragma unroll
    for (int i = 0; i < 4; i++)
#pragma unroll
        for (int q = 0; q < 11; q++) dp[i][q] = wave_sum63(dp[i][q]);

    float local = 0.f;
    if (lane == 63) {
        const float w1 = 1.0f / ((float)B * (float)(S - 1));
        const float w2 = 1.0f / ((float)B * (float)(10 * S - 145));
        float no[4];
#pragma unroll
        for (int i = 0; i < 4; i++) no[i] = sqrtf(n2o[i]);
        float nx[14];
#pragma unroll
        for (int j = 0; j < 14; j++) nx[j] = sqrtf(n2x[j]);

#pragma unroll
        for (int i = 0; i < 4; i++) {
            const int t = t0 + i;
            if (t + 1 < S) {
                const float nb = (i < 3) ? no[i + 1] : nx[0];
                const float sim = dp[i][0] / fmaxf(no[i] * nb, EPS);
                local += w1 * (1.0f - sim);
            }
#pragma unroll
            for (int k = 10; k <= 19; k++) {
                if (t + k < S) {
                    const float nb = nx[i + k - 9];
                    const float sim = dp[i][k - 9] / fmaxf(no[i] * nb, EPS);
                    const float r = MARGIN - sim;
                    local += w2 * (r > 0.f ? r : 0.f);
                }
            }
        }
    }

    __shared__ float bsum[4];
    if (lane == 63) bsum[wslot] = local;
    __syncthreads();
    if (threadIdx.x == 0)
        ws[blockIdx.x] = bsum[0] + bsum[1] + bsum[2] + bsum[3];
}

__global__ __launch_bounds__(1024) void tcl_final(const float* __restrict__ ws,
                                                  float* __restrict__ out) {
    float v = 0.f;
    for (int j = threadIdx.x; j < NBLOCKS; j += 1024) v += ws[j];
    v = wave_sum63(v);
    __shared__ float s[16];
    if ((threadIdx.x & 63) == 63) s[threadIdx.x >> 6] = v;
    __syncthreads();
    if (threadIdx.x == 0) {
        float t = 0.f;
#pragma unroll
        for (int j = 0; j < 16; j++) t += s[j];
        out[0] = t;
    }
}

extern "C" void kernel_launch(void* const* d_in, const int* in_sizes, int n_in,
                              void* d_out, int out_size, void* d_ws, size_t ws_size,
                              hipStream_t stream) {
    const float* h = (const float*)d_in[0];
    float* out = (float*)d_out;
    float* ws = (float*)d_ws;  // needs NBLOCKS * 4 = 16 KB
    tcl_partial<<<NBLOCKS, 256, 0, stream>>>(h, ws);
    tcl_final<<<1, 1024, 0, stream>>>(ws, out);
}

// Round 3
// 208.632 us; speedup vs baseline: 1.0644x; 1.0022x over previous
//
#include <hip/hip_runtime.h>
#include <math.h>

// Problem constants (fixed by setup_inputs): h [B=16, S=4096, D=512] fp32.
constexpr int B = 16;
constexpr int S = 4096;
constexpr int D = 512;
constexpr float MARGIN = 0.5f;
constexpr float EPS = 1e-8f;

constexpr int TG = 4;                               // t's per wave
constexpr int GROUPS_PER_BATCH = S / TG;            // 1024
constexpr int TOTAL_WAVES = B * GROUPS_PER_BATCH;   // 16384
constexpr int NBLOCKS = TOTAL_WAVES / 4;            // 4096

__device__ inline float dot8(const float4& x0, const float4& x1,
                             const float4& y0, const float4& y1) {
    return x0.x * y0.x + x0.y * y0.y + x0.z * y0.z + x0.w * y0.w +
           x1.x * y1.x + x1.y * y1.y + x1.z * y1.z + x1.w * y1.w;
}

// v_add_f32_dpp step: x += dpp_move(x). old=0 + bound_ctrl(zero-fill) makes
// invalid-source lanes add 0 — unconditionally safe for sum reductions.
template <int CTRL>
__device__ __forceinline__ float dpp_add(float x) {
    int m = __builtin_amdgcn_update_dpp(0, __float_as_int(x), CTRL, 0xf, 0xf, true);
    return x + __int_as_float(m);
}

// Full wave64 sum via DPP (pure VALU, no LDS path). Result valid in lane 63.
__device__ __forceinline__ float wave_sum63(float x) {
    x = dpp_add<0x111>(x);  // row_shr:1
    x = dpp_add<0x112>(x);  // row_shr:2
    x = dpp_add<0x114>(x);  // row_shr:4
    x = dpp_add<0x118>(x);  // row_shr:8  -> lanes 15/31/47/63 hold row sums
    x = dpp_add<0x142>(x);  // row_bcast:15 -> lane31 += lane15, lane63 += lane47
    x = dpp_add<0x143>(x);  // row_bcast:31 -> lane63 += lane31
    return x;
}

// __launch_bounds__(256, 2): 2 waves/SIMD -> 256-VGPR budget. We deliberately
// trade occupancy for register space so ALL 18 row-loads can be in flight
// before any compute (latency was the R2 bottleneck, not BW or issue).
__global__ __launch_bounds__(256, 2) void tcl_partial(const float* __restrict__ h,
                                                      float* __restrict__ ws) {
    const int lane  = threadIdx.x & 63;
    const int wslot = threadIdx.x >> 6;
    const int wid   = blockIdx.x * 4 + wslot;
    const int b     = wid >> 10;               // GROUPS_PER_BATCH = 1024
    const int t0    = (wid & 1023) * TG;
    const float* base = h + (size_t)b * S * D + lane * 8;

    // ---- Phase 1: issue ALL loads (36 x global_load_dwordx4), no consumers ----
    float4 a0[4], a1[4];
#pragma unroll
    for (int i = 0; i < 4; i++) {
        const float* q = base + (size_t)(t0 + i) * D;
        a0[i] = *(const float4*)q;
        a1[i] = *(const float4*)(q + 4);
    }
    float4 c0[14], c1[14];
#pragma unroll
    for (int j = 0; j < 14; j++) {
        const int off = (j == 0) ? 4 : (9 + j);
        const int s = t0 + off;
        c0[j] = make_float4(0.f, 0.f, 0.f, 0.f);
        c1[j] = make_float4(0.f, 0.f, 0.f, 0.f);
        if (s < S) {
            const float* q = base + (size_t)s * D;
            c0[j] = *(const float4*)q;
            c1[j] = *(const float4*)(q + 4);
        }
    }

    // ---- Phase 2: all dot products (per-lane partials) ----
    float n2o[4];
#pragma unroll
    for (int i = 0; i < 4; i++) n2o[i] = dot8(a0[i], a1[i], a0[i], a1[i]);

    float n2x[14];
#pragma unroll
    for (int j = 0; j < 14; j++) n2x[j] = dot8(c0[j], c1[j], c0[j], c1[j]);

    float dp[4][11];  // [i][0] = k=1 ; [i][1..10] = k=10..19
#pragma unroll
    for (int i = 0; i < 4; i++)
#pragma unroll
        for (int q = 0; q < 11; q++) dp[i][q] = 0.f;

    // k=1 dots
    dp[0][0] = dot8(a0[0], a1[0], a0[1], a1[1]);
    dp[1][0] = dot8(a0[1], a1[1], a0[2], a1[2]);
    dp[2][0] = dot8(a0[2], a1[2], a0[3], a1[3]);
    dp[3][0] = dot8(a0[3], a1[3], c0[0], c1[0]);  // (t0+3, t0+4)

    // distant dots: cross row j>=1 is t0+9+j; pairs with own row i when
    // k = 9+j-i in [10,19]
#pragma unroll
    for (int j = 1; j < 14; j++) {
#pragma unroll
        for (int i = 0; i < 4; i++) {
            const int k = 9 + j - i;
            if (k >= 10 && k <= 19)
                dp[i][k - 9] += dot8(a0[i], a1[i], c0[j], c1[j]);
        }
    }

    // ---- Phase 3: DPP wave reduction of all 62 partials (lane 63) ----
#pragma unroll
    for (int i = 0; i < 4; i++) n2o[i] = wave_sum63(n2o[i]);
#pragma unroll
    for (int j = 0; j < 14; j++) n2x[j] = wave_sum63(n2x[j]);
#pragma unroll
    for (int i = 0; i < 4; i++)
#pragma unroll
        for (int q = 0; q < 11; q++) dp[i][q] = wave_sum63(dp[i][q]);

    // ---- Phase 4: epilogue on lane 63 ----
    float local = 0.f;
    if (lane == 63) {
        const float w1 = 1.0f / ((float)B * (float)(S - 1));
        const float w2 = 1.0f / ((float)B * (float)(10 * S - 145));
        float no[4];
#pragma unroll
        for (int i = 0; i < 4; i++) no[i] = sqrtf(n2o[i]);
        float nx[14];
#pragma unroll
        for (int j = 0; j < 14; j++) nx[j] = sqrtf(n2x[j]);

#pragma unroll
        for (int i = 0; i < 4; i++) {
            const int t = t0 + i;
            if (t + 1 < S) {
                const float nb = (i < 3) ? no[i + 1] : nx[0];
                const float sim = dp[i][0] / fmaxf(no[i] * nb, EPS);
                local += w1 * (1.0f - sim);
            }
#pragma unroll
            for (int k = 10; k <= 19; k++) {
                if (t + k < S) {
                    const float nb = nx[i + k - 9];
                    const float sim = dp[i][k - 9] / fmaxf(no[i] * nb, EPS);
                    const float r = MARGIN - sim;
                    local += w2 * (r > 0.f ? r : 0.f);
                }
            }
        }
    }

    __shared__ float bsum[4];
    if (lane == 63) bsum[wslot] = local;
    __syncthreads();
    if (threadIdx.x == 0)
        ws[blockIdx.x] = bsum[0] + bsum[1] + bsum[2] + bsum[3];
}

__global__ __launch_bounds__(1024) void tcl_final(const float* __restrict__ ws,
                                                  float* __restrict__ out) {
    float v = 0.f;
    for (int j = threadIdx.x; j < NBLOCKS; j += 1024) v += ws[j];
    v = wave_sum63(v);
    __shared__ float s[16];
    if ((threadIdx.x & 63) == 63) s[threadIdx.x >> 6] = v;
    __syncthreads();
    if (threadIdx.x == 0) {
        float t = 0.f;
#pragma unroll
        for (int j = 0; j < 16; j++) t += s[j];
        out[0] = t;
    }
}

extern "C" void kernel_launch(void* const* d_in, const int* in_sizes, int n_in,
                              void* d_out, int out_size, void* d_ws, size_t ws_size,
                              hipStream_t stream) {
    const float* h = (const float*)d_in[0];
    float* out = (float*)d_out;
    float* ws = (float*)d_ws;  // needs NBLOCKS * 4 = 16 KB
    tcl_partial<<<NBLOCKS, 256, 0, stream>>>(h, ws);
    tcl_final<<<1, 1024, 0, stream>>>(ws, out);
}